// Round 1
// baseline (211.067 us; speedup 1.0000x reference)
//
#include <hip/hip_runtime.h>

#define TT  200
#define IN  5
#define NH  32
#define FC1 20

// One wave (64 threads) per batch element. Lane l = (u = l&31, p = l>>5).
// Lane owns gate rows r0 = u + 32p (i|f) and r1 = u + 64 + 32p (g|o),
// weights resident in VGPRs. h/h20 broadcast through LDS (uniform reads).
__global__ __launch_bounds__(64) void lstm_fused(
    const float* __restrict__ x,      // [B,200,5]
    const float* __restrict__ fc1_w,  // [20,5]
    const float* __restrict__ fc1_b,  // [20]
    const float* __restrict__ w_ih,   // [128,20]
    const float* __restrict__ w_hh,   // [128,32]
    const float* __restrict__ b_ih,   // [128]
    const float* __restrict__ b_hh,   // [128]
    const float* __restrict__ fc2_w,  // [2,32]
    const float* __restrict__ fc2_b,  // [2]
    float* __restrict__ out)          // [B,2]
{
    const int b = blockIdx.x;
    const int l = threadIdx.x;
    const int u = l & 31;
    const int p = l >> 5;

    __shared__ __align__(16) float x_lds[TT * IN];   // 4 KB
    __shared__ __align__(16) float h20_lds[FC1];
    __shared__ __align__(16) float h_lds[NH];

    // ---- stage this batch's x into LDS (coalesced float4) ----
    {
        const float4* xg = (const float4*)(x + (size_t)b * (TT * IN));
        float4* xl = (float4*)x_lds;
        #pragma unroll
        for (int i = 0; i < 4; ++i) {
            int idx = l + 64 * i;
            if (idx < (TT * IN) / 4) xl[idx] = xg[idx];
        }
    }

    // ---- load this lane's weight rows into registers ----
    const int r0 = u + 32 * p;      // i (p=0) | f (p=1)
    const int r1 = r0 + 64;         // g (p=0) | o (p=1)
    float wih0[FC1], wih1[FC1], whh0[NH], whh1[NH];
    {
        const float4* a0p = (const float4*)(w_ih + r0 * FC1);
        const float4* a1p = (const float4*)(w_ih + r1 * FC1);
        #pragma unroll
        for (int j = 0; j < FC1 / 4; ++j) {
            float4 va = a0p[j], vb = a1p[j];
            wih0[4*j+0]=va.x; wih0[4*j+1]=va.y; wih0[4*j+2]=va.z; wih0[4*j+3]=va.w;
            wih1[4*j+0]=vb.x; wih1[4*j+1]=vb.y; wih1[4*j+2]=vb.z; wih1[4*j+3]=vb.w;
        }
        const float4* c0p = (const float4*)(w_hh + r0 * NH);
        const float4* c1p = (const float4*)(w_hh + r1 * NH);
        #pragma unroll
        for (int j = 0; j < NH / 4; ++j) {
            float4 va = c0p[j], vb = c1p[j];
            whh0[4*j+0]=va.x; whh0[4*j+1]=va.y; whh0[4*j+2]=va.z; whh0[4*j+3]=va.w;
            whh1[4*j+0]=vb.x; whh1[4*j+1]=vb.y; whh1[4*j+2]=vb.z; whh1[4*j+3]=vb.w;
        }
    }
    const float bias0 = b_ih[r0] + b_hh[r0];
    const float bias1 = b_ih[r1] + b_hh[r1];

    // fc1 weights for the p==1, u<20 lanes (they produce h20 for the next step)
    float fw[IN] = {0.f, 0.f, 0.f, 0.f, 0.f};
    float fb = 0.f;
    const bool is_fc1 = (p == 1) && (u < FC1);
    if (is_fc1) {
        #pragma unroll
        for (int i = 0; i < IN; ++i) fw[i] = fc1_w[u * IN + i];
        fb = fc1_b[u];
    }

    // activation constants for the r1 gate: tanh (p=0) vs sigmoid (p=1)
    const float An = (p == 0) ? 2.f : 1.f;
    const float Bn = (p == 0) ? -2.f : -1.f;
    const float Cn = (p == 0) ? -1.f : 0.f;

    __syncthreads();   // x_lds staged

    // init h = 0 and h20 for t = 0
    if (l < NH) h_lds[l] = 0.f;
    if (is_fc1) {
        float acc = fb;
        #pragma unroll
        for (int i = 0; i < IN; ++i) acc = fmaf(fw[i], x_lds[i], acc);
        h20_lds[u] = fmaxf(acc, 0.f);
    }
    float c = 0.f;
    __syncthreads();

    for (int t = 0; t < TT; ++t) {
        // broadcast-read h20[t] and h[t-1] (uniform-address ds_read_b128)
        float h20r[FC1], hr[NH];
        {
            const float4* q = (const float4*)h20_lds;
            #pragma unroll
            for (int j = 0; j < FC1 / 4; ++j) {
                float4 v = q[j];
                h20r[4*j+0]=v.x; h20r[4*j+1]=v.y; h20r[4*j+2]=v.z; h20r[4*j+3]=v.w;
            }
            const float4* q2 = (const float4*)h_lds;
            #pragma unroll
            for (int j = 0; j < NH / 4; ++j) {
                float4 v = q2[j];
                hr[4*j+0]=v.x; hr[4*j+1]=v.y; hr[4*j+2]=v.z; hr[4*j+3]=v.w;
            }
        }

        // two gate rows, each with 2 split accumulators (break dep chains)
        float a0a = bias0, a0b = 0.f, a1a = bias1, a1b = 0.f;
        #pragma unroll
        for (int j = 0; j < FC1; j += 2) {
            a0a = fmaf(wih0[j],   h20r[j],   a0a);
            a0b = fmaf(wih0[j+1], h20r[j+1], a0b);
            a1a = fmaf(wih1[j],   h20r[j],   a1a);
            a1b = fmaf(wih1[j+1], h20r[j+1], a1b);
        }
        #pragma unroll
        for (int k = 0; k < NH; k += 2) {
            a0a = fmaf(whh0[k],   hr[k],   a0a);
            a0b = fmaf(whh0[k+1], hr[k+1], a0b);
            a1a = fmaf(whh1[k],   hr[k],   a1a);
            a1b = fmaf(whh1[k+1], hr[k+1], a1b);
        }
        const float a0 = a0a + a0b;
        const float a1 = a1a + a1b;

        // s0 = sigmoid(a0) always; s1 = tanh(a1) for p=0, sigmoid(a1) for p=1
        const float s0 = __builtin_amdgcn_rcpf(1.f + __expf(-a0));
        const float e1 = __expf(Bn * a1);
        const float s1 = fmaf(An, __builtin_amdgcn_rcpf(1.f + e1), Cn);

        // bring f and o to the p=0 lanes
        const float fg = __shfl_xor(s0, 32);
        const float og = __shfl_xor(s1, 32);

        if (p == 0) {
            // lane u: i=s0, g=s1, f=fg, o=og
            c = fmaf(fg, c, s0 * s1);
            const float tc = fmaf(2.f, __builtin_amdgcn_rcpf(1.f + __expf(-2.f * c)), -1.f);
            h_lds[u] = og * tc;
        } else if (u < FC1) {
            if (t + 1 < TT) {
                float acc = fb;
                #pragma unroll
                for (int i = 0; i < IN; ++i) acc = fmaf(fw[i], x_lds[(t + 1) * IN + i], acc);
                h20_lds[u] = fmaxf(acc, 0.f);
            }
        }
        __syncthreads();   // single-wave block: cheap; orders LDS writes vs next reads
    }

    // fc2 on final h
    if (l < 2) {
        float acc = fc2_b[l];
        #pragma unroll
        for (int k = 0; k < NH; ++k) acc = fmaf(fc2_w[l * NH + k], h_lds[k], acc);
        out[(size_t)b * 2 + l] = acc;
    }
}

extern "C" void kernel_launch(void* const* d_in, const int* in_sizes, int n_in,
                              void* d_out, int out_size, void* d_ws, size_t ws_size,
                              hipStream_t stream) {
    const float* x     = (const float*)d_in[0];
    const float* fc1_w = (const float*)d_in[1];
    const float* fc1_b = (const float*)d_in[2];
    const float* w_ih  = (const float*)d_in[3];
    const float* w_hh  = (const float*)d_in[4];
    const float* b_ih  = (const float*)d_in[5];
    const float* b_hh  = (const float*)d_in[6];
    const float* fc2_w = (const float*)d_in[7];
    const float* fc2_b = (const float*)d_in[8];
    float* out = (float*)d_out;

    const int B = in_sizes[0] / (TT * IN);
    lstm_fused<<<dim3(B), dim3(64), 0, stream>>>(
        x, fc1_w, fc1_b, w_ih, w_hh, b_ih, b_hh, fc2_w, fc2_b, out);
}

// Round 2
// 200.507 us; speedup vs baseline: 1.0527x; 1.0527x over previous
//
#include <hip/hip_runtime.h>

#define TT  200
#define IN  5
#define NH  32
#define FC1 20
#define KD  (FC1 + NH)   // 52 combined input dims: [h20(20), h(32)]

typedef float f2 __attribute__((ext_vector_type(2)));

// One wave (64 threads) per batch element. Lane l = (u = l&31, p = l>>5).
// Lane owns gate rows r0 = u + 32p (i|f) and r1 = r0 + 64 (g|o).
// Weights packed as float2 and pinned in VGPRs; h20/h broadcast via LDS.
// Single-wave workgroup -> LDS ops are wave-FIFO ordered -> no barriers.
__global__ __launch_bounds__(64, 2) void lstm_fused(
    const float* __restrict__ x,      // [B,200,5]
    const float* __restrict__ fc1_w,  // [20,5]
    const float* __restrict__ fc1_b,  // [20]
    const float* __restrict__ w_ih,   // [128,20]
    const float* __restrict__ w_hh,   // [128,32]
    const float* __restrict__ b_ih,   // [128]
    const float* __restrict__ b_hh,   // [128]
    const float* __restrict__ fc2_w,  // [2,32]
    const float* __restrict__ fc2_b,  // [2]
    float* __restrict__ out)          // [B,2]
{
    const int b = blockIdx.x;
    const int l = threadIdx.x;
    const int u = l & 31;
    const int p = l >> 5;

    __shared__ __align__(16) float x_lds[TT * IN + 12];  // pad: tail step reads t+1
    __shared__ __align__(16) float sh_in[56];            // [0,20)=h20, [20,52)=h

    // ---- stage this batch's x into LDS (coalesced float4) ----
    {
        const float4* xg = (const float4*)(x + (size_t)b * (TT * IN));
        float4* xl = (float4*)x_lds;
        #pragma unroll
        for (int i = 0; i < 4; ++i) {
            int idx = l + 64 * i;
            if (idx < (TT * IN) / 4) xl[idx] = xg[idx];
        }
        if (l < 12) x_lds[TT * IN + l] = 0.f;   // deterministic pad
    }

    // ---- load this lane's two weight rows as float2 pairs, pin in VGPRs ----
    const int r0 = u + 32 * p;      // i (p=0) | f (p=1)
    const int r1 = r0 + 64;         // g (p=0) | o (p=1)
    f2 w0[KD / 2], w1[KD / 2];      // row-major: [w_ih(20), w_hh(32)]
    {
        const float4* a0p = (const float4*)(w_ih + r0 * FC1);
        const float4* a1p = (const float4*)(w_ih + r1 * FC1);
        #pragma unroll
        for (int j = 0; j < FC1 / 4; ++j) {
            float4 va = a0p[j], vb = a1p[j];
            w0[2*j]   = f2{va.x, va.y};  w0[2*j+1] = f2{va.z, va.w};
            w1[2*j]   = f2{vb.x, vb.y};  w1[2*j+1] = f2{vb.z, vb.w};
        }
        const float4* c0p = (const float4*)(w_hh + r0 * NH);
        const float4* c1p = (const float4*)(w_hh + r1 * NH);
        #pragma unroll
        for (int j = 0; j < NH / 4; ++j) {
            float4 va = c0p[j], vb = c1p[j];
            w0[FC1/2 + 2*j]   = f2{va.x, va.y};  w0[FC1/2 + 2*j+1] = f2{va.z, va.w};
            w1[FC1/2 + 2*j]   = f2{vb.x, vb.y};  w1[FC1/2 + 2*j+1] = f2{vb.z, vb.w};
        }
        // pin: make values opaque so LICM/remat can't sink the loads into the loop
        #pragma unroll
        for (int j = 0; j < KD / 2; ++j) {
            asm volatile("" : "+v"(w0[j]));
            asm volatile("" : "+v"(w1[j]));
        }
    }
    const float bias0 = b_ih[r0] + b_hh[r0];
    const float bias1 = b_ih[r1] + b_hh[r1];

    // fc1 weights for the p==1, u<20 lanes (they produce h20 for the next step)
    float fw[IN] = {0.f, 0.f, 0.f, 0.f, 0.f};
    float fb = 0.f;
    const bool is_fc1 = (p == 1) && (u < FC1);
    if (is_fc1) {
        #pragma unroll
        for (int i = 0; i < IN; ++i) fw[i] = fc1_w[u * IN + i];
        fb = fc1_b[u];
    }

    // activation constants for the r1 gate: tanh (p=0) vs sigmoid (p=1)
    const float An = (p == 0) ? 2.f : 1.f;
    const float Bn = (p == 0) ? -2.f : -1.f;
    const float Cn = (p == 0) ? -1.f : 0.f;

    // init: h = 0; h20 for t = 0   (single wave: DS FIFO order, no barrier)
    if (l < 56) sh_in[l] = 0.f;
    asm volatile("" ::: "memory");
    if (is_fc1) {
        float acc = fb;
        #pragma unroll
        for (int i = 0; i < IN; ++i) acc = fmaf(fw[i], x_lds[i], acc);
        sh_in[u] = fmaxf(acc, 0.f);
    }
    asm volatile("" ::: "memory");
    float c = 0.f;

    for (int t = 0; t < TT; ++t) {
        // broadcast-read the combined [h20|h] vector (13x uniform ds_read_b128)
        f2 in2[KD / 2];
        {
            const float4* q = (const float4*)sh_in;
            #pragma unroll
            for (int j = 0; j < 13; ++j) {
                float4 v = q[j];
                in2[2*j]   = f2{v.x, v.y};
                in2[2*j+1] = f2{v.z, v.w};
            }
        }

        // two gate rows, packed FMA, 2 split accumulators each
        f2 A0 = f2{bias0, 0.f}, B0 = f2{0.f, 0.f};
        f2 A1 = f2{bias1, 0.f}, B1 = f2{0.f, 0.f};
        #pragma unroll
        for (int j = 0; j < KD / 2; j += 2) {
            A0 = __builtin_elementwise_fma(w0[j],   in2[j],   A0);
            B0 = __builtin_elementwise_fma(w0[j+1], in2[j+1], B0);
            A1 = __builtin_elementwise_fma(w1[j],   in2[j],   A1);
            B1 = __builtin_elementwise_fma(w1[j+1], in2[j+1], B1);
        }
        A0 += B0; A1 += B1;
        const float a0 = A0.x + A0.y;
        const float a1 = A1.x + A1.y;

        // s0 = sigmoid(a0) always; s1 = tanh(a1) for p=0, sigmoid(a1) for p=1
        const float s0 = __builtin_amdgcn_rcpf(1.f + __expf(-a0));
        const float e1 = __expf(Bn * a1);
        const float s1 = fmaf(An, __builtin_amdgcn_rcpf(1.f + e1), Cn);

        // bring f and o to the p=0 lanes
        const float fg = __shfl_xor(s0, 32);
        const float og = __shfl_xor(s1, 32);

        if (p == 0) {
            // lane u: i=s0, g=s1, f=fg, o=og
            c = fmaf(fg, c, s0 * s1);
            const float tc = fmaf(2.f, __builtin_amdgcn_rcpf(1.f + __expf(-2.f * c)), -1.f);
            sh_in[FC1 + u] = og * tc;
        } else if (u < FC1) {
            float acc = fb;
            #pragma unroll
            for (int i = 0; i < IN; ++i) acc = fmaf(fw[i], x_lds[(t + 1) * IN + i], acc);
            sh_in[u] = fmaxf(acc, 0.f);
        }
        asm volatile("" ::: "memory");  // compiler fence; HW: wave DS ops are FIFO
    }

    // fc2 on final h
    if (l < 2) {
        float acc = fc2_b[l];
        #pragma unroll
        for (int k = 0; k < NH; ++k) acc = fmaf(fc2_w[l * NH + k], sh_in[FC1 + k], acc);
        out[(size_t)b * 2 + l] = acc;
    }
}

extern "C" void kernel_launch(void* const* d_in, const int* in_sizes, int n_in,
                              void* d_out, int out_size, void* d_ws, size_t ws_size,
                              hipStream_t stream) {
    const float* x     = (const float*)d_in[0];
    const float* fc1_w = (const float*)d_in[1];
    const float* fc1_b = (const float*)d_in[2];
    const float* w_ih  = (const float*)d_in[3];
    const float* w_hh  = (const float*)d_in[4];
    const float* b_ih  = (const float*)d_in[5];
    const float* b_hh  = (const float*)d_in[6];
    const float* fc2_w = (const float*)d_in[7];
    const float* fc2_b = (const float*)d_in[8];
    float* out = (float*)d_out;

    const int B = in_sizes[0] / (TT * IN);
    lstm_fused<<<dim3(B), dim3(64), 0, stream>>>(
        x, fc1_w, fc1_b, w_ih, w_hh, b_ih, b_hh, fc2_w, fc2_b, out);
}